// Round 5
// baseline (232.123 us; speedup 1.0000x reference)
//
#include <hip/hip_runtime.h>
#include <hip/hip_bf16.h>
#include <hip/hip_cooperative_groups.h>
#include <math.h>

typedef __attribute__((ext_vector_type(8))) short bf16x8v;
typedef __attribute__((ext_vector_type(4))) float f32x4v;
typedef __attribute__((ext_vector_type(4))) unsigned u32x4v;

namespace cg = cooperative_groups;

namespace {

constexpr float PI_F      = 3.14159265358979323846f;
constexpr float TWO_PI_F  = 6.28318530717958647692f;
constexpr float INV_2PI_F = 0.15915494309189533577f;
constexpr float ZC_F      = 0.86602540378443864676f;

__device__ __constant__ float d_BOUNDS[8] = {0.1f, 0.2f, 0.4f, 0.6f, 0.75f,
                                             0.8660254037844386f, 0.92f, 0.97f};
__device__ __constant__ float d_PARITY[6] = {1.f, -1.f, 1.f, 1.f, -1.f, -1.f};
__device__ __constant__ int d_LEGAL[9][6] = {
    {0, 0, 0, 1, 1, 1},
    {1, 0, 1, 0, 1, 1},
    {1, 1, 1, 0, 1, 1},
    {0, 1, 0, 1, 1, 1},
    {1, 1, 1, 1, 1, 1},
    {0, 1, 0, 1, 1, 1},
    {0, 1, 0, 1, 0, 0},
    {0, 1, 1, 1, 0, 0},
    {0, 1, 1, 1, 0, 0}};

__device__ __forceinline__ float wave_sum(float v) {
#pragma unroll
  for (int o = 32; o > 0; o >>= 1) v += __shfl_xor(v, o, 64);
  return v;
}

__device__ __forceinline__ float gelu_exact(float x) {
  return 0.5f * x * (1.0f + erff(x * 0.70710678118654752440f));
}

__device__ __forceinline__ unsigned short f2b(float v) {
  return __builtin_bit_cast(unsigned short, __float2bfloat16(v));
}

__device__ __forceinline__ unsigned pkbf(float a, float b) {
  return ((unsigned)f2b(b) << 16) | (unsigned)f2b(a);
}

}  // namespace

// D-layout -> B-frag redistribution (verified rounds 3/4): lane needs
// sd[m0|m1][0..1] from lanes srcA/srcB; select by hi = (g>=2).
#define ASM_FRAG(dst, arr, m0, m1)                                     \
  {                                                                    \
    const unsigned q0 = (unsigned)__shfl((int)arr[m0][0], srcA, 64);   \
    const unsigned q1 = (unsigned)__shfl((int)arr[m1][0], srcA, 64);   \
    const unsigned q2 = (unsigned)__shfl((int)arr[m0][1], srcA, 64);   \
    const unsigned q3 = (unsigned)__shfl((int)arr[m1][1], srcA, 64);   \
    const unsigned q4 = (unsigned)__shfl((int)arr[m0][0], srcB, 64);   \
    const unsigned q5 = (unsigned)__shfl((int)arr[m1][0], srcB, 64);   \
    const unsigned q6 = (unsigned)__shfl((int)arr[m0][1], srcB, 64);   \
    const unsigned q7 = (unsigned)__shfl((int)arr[m1][1], srcB, 64);   \
    u32x4v tq;                                                         \
    tq[0] = hi ? q1 : q0;                                              \
    tq[1] = hi ? q3 : q2;                                              \
    tq[2] = hi ? q5 : q4;                                              \
    tq[3] = hi ? q7 : q6;                                              \
    dst = __builtin_bit_cast(bf16x8v, tq);                             \
  }

struct Params {
  const float *x, *W_enc, *b_enc, *K, *omega, *Kglob, *aplK, *aplOm;
  const float *W1, *b1, *W2, *b2, *W3, *b3, *prior, *noise, *W_out, *b_out;
  unsigned short *Aenc, *Aout;
  float *part, *row0, *coh0, *out;
};

// ---------------------------------------------------------------------------
// One cooperative kernel: prep -> enc -> 4x(decide+kura) -> out.
// 256 blocks x 128 thr (2 waves; wave handles 16 batch cols). State lives in
// registers in the MFMA D-layout (col=lane&15=batch, row=16m+4g+r=osc) for
// the entire network. grid.sync() only where the batch-wide z is needed.
// ---------------------------------------------------------------------------
__global__ __launch_bounds__(128, 1) void fused_net(Params p) {
  cg::grid_group gridg = cg::this_grid();
  __shared__ float fe[64], hh[64], lgits[8], scal[4], redz[2];
  __shared__ __align__(16) float trans[2][16][260];  // stride 260: no 16-way bank conflict
  const int tid = threadIdx.x;
  const int w = tid >> 6;
  const int lane = tid & 63;
  const int c = lane & 15, g = lane >> 4;
  const bool hi = g >= 2;
  const int bid = blockIdx.x;
  const int b = bid * 32 + w * 16 + c;
  const int srcA = ((2 * g) & 3) * 16 + c;
  const int srcB = srcA + 16;

  // ---- prep: Aenc [64][512], Aout [256][128] bf16 (1 elem/thread each) ----
  {
    const int t = bid * 128 + tid;
    const int o = t >> 9, k = t & 511;
    p.Aenc[t] = f2b((o < 60) ? p.W_enc[k * 60 + o] : 0.f);
    const int d = t >> 7, kk = t & 127, prt = kk >> 6, oo = kk & 63;
    p.Aout[t] = f2b((oo < 60) ? p.W_out[(prt * 60 + oo) * 256 + d] : 0.f);
  }
  gridg.sync();

  float th[4][4], s[4][4], cc[4][4], chcol;

  // ---- encoder: theta = pi*tanh(x @ W_enc + b_enc) ----
  {
    const f32x4v zz = {0.f, 0.f, 0.f, 0.f};
    f32x4v em[4] = {zz, zz, zz, zz};
    const float* xr = p.x + (size_t)b * 512 + 8 * g;
#pragma unroll 4
    for (int kt = 0; kt < 16; ++kt) {
      const float4 u0 = *(const float4*)(xr + 32 * kt);
      const float4 u1 = *(const float4*)(xr + 32 * kt + 4);
      u32x4v bx;
      bx[0] = pkbf(u0.x, u0.y); bx[1] = pkbf(u0.z, u0.w);
      bx[2] = pkbf(u1.x, u1.y); bx[3] = pkbf(u1.z, u1.w);
      const bf16x8v Bx = __builtin_bit_cast(bf16x8v, bx);
#pragma unroll
      for (int m = 0; m < 4; ++m) {
        const bf16x8v Aa = *(const bf16x8v*)(p.Aenc + (16 * m + c) * 512 + 32 * kt + 8 * g);
        em[m] = __builtin_amdgcn_mfma_f32_16x16x32_bf16(Aa, Bx, em[m], 0, 0, 0);
      }
    }
    float pc = 0.f, ps = 0.f;
#pragma unroll
    for (int m = 0; m < 4; ++m) {
      float4 be;
      if (m == 3 && g == 3) be = make_float4(0.f, 0.f, 0.f, 0.f);
      else be = *(const float4*)(p.b_enc + 16 * m + 4 * g);
      const float bea[4] = {be.x, be.y, be.z, be.w};
#pragma unroll
      for (int r = 0; r < 4; ++r) {
        const int o = 16 * m + 4 * g + r;
        th[m][r] = (o < 60) ? PI_F * tanhf(em[m][r] + bea[r]) : 0.f;
        s[m][r] = __sinf(th[m][r]);
        cc[m][r] = __cosf(th[m][r]);
        pc += cc[m][r]; ps += s[m][r];
      }
    }
    pc += __shfl_xor(pc, 16); pc += __shfl_xor(pc, 32);
    ps += __shfl_xor(ps, 16); ps += __shfl_xor(ps, 32);
    const float mc = (pc - 4.f) * (1.f / 60.f);
    const float ms = ps * (1.f / 60.f);
    chcol = sqrtf(mc * mc + ms * ms);
  }
  // z-partial + publish row0 (buffer 0)
  {
    const float tot = wave_sum(chcol) * 0.25f;
    if (lane == 0) redz[w] = tot;
    __syncthreads();
    if (tid == 0) p.part[bid] = redz[0] + redz[1];
    if (bid == 0 && w == 0 && c == 0) {
#pragma unroll
      for (int m = 0; m < 4; ++m)
#pragma unroll
        for (int r = 0; r < 4; ++r) {
          const int o = 16 * m + 4 * g + r;
          if (o < 60) p.row0[o] = cc[m][r];
        }
    }
    if (bid == 0 && tid == 0) p.coh0[0] = chcol;
  }
  gridg.sync();

#pragma unroll 1
  for (int l = 0; l < 4; ++l) {
    // ---- decide (wave 0 of every block, redundant but parallel) ----
    float z = 0.f;
    int tier = 0;
    if (tid < 64) {
      const float4 pv = *(const float4*)(p.part + l * 256 + 4 * lane);
      z = wave_sum(pv.x + pv.y + pv.z + pv.w) * (1.f / 8192.f);
#pragma unroll
      for (int i = 0; i < 8; ++i) tier += (z >= d_BOUNDS[i]) ? 1 : 0;
      const float dsneg = expf(-36.f * (z - ZC_F) * (z - ZC_F));
      const float* row0 = p.row0 + 64 * (l & 1);
      fe[lane] = (lane < 60) ? row0[lane]
               : (lane == 60) ? z
               : (lane == 61) ? p.coh0[l & 1]
               : (lane == 62) ? dsneg
                              : (float)(tier + 1) * (1.f / 9.f);
    }
    __syncthreads();
    if (tid < 64) {
      float a1 = p.b1[l * 64 + lane];
#pragma unroll 8
      for (int k = 0; k < 64; ++k) a1 = fmaf(fe[k], p.W1[l * 4096 + k * 64 + lane], a1);
      hh[lane] = gelu_exact(a1);
    }
    __syncthreads();
    float a2v = 0.f;
    if (tid < 64) {
      a2v = p.b2[l * 64 + lane];
#pragma unroll 8
      for (int k = 0; k < 64; ++k) a2v = fmaf(hh[k], p.W2[l * 4096 + k * 64 + lane], a2v);
    }
    __syncthreads();
    if (tid < 64) fe[lane] = gelu_exact(a2v);
    __syncthreads();
    if (tid < 6) {
      float a3 = p.b3[l * 6 + tid] + p.prior[l * 6 + tid];
#pragma unroll 8
      for (int k = 0; k < 64; ++k) a3 = fmaf(fe[k], p.W3[l * 384 + k * 6 + tid], a3);
      lgits[tid] = a3;
    }
    __syncthreads();
    if (tid == 0) {
      int idx = 0;
      float best = -INFINITY;
#pragma unroll
      for (int m2 = 0; m2 < 6; ++m2)
        if (d_LEGAL[tier][m2] && lgits[m2] > best) { best = lgits[m2]; idx = m2; }
      const float par = d_PARITY[idx];
      scal[0] = (idx == 1) ? 0.1f : ((idx == 5) ? -0.1f : 0.f);
      scal[1] = (idx == 4) ? 1.f : 0.f;
      scal[2] = (1.f + par * (p.aplK[l * 6 + idx] * z) * 0.5f) * 0.1f * p.Kglob[l] * (1.f / 60.f);
      scal[3] = p.aplOm[l * 6 + idx] * par;
    }
    __syncthreads();
    const float coef = scal[0], dm = scal[1], ktot = scal[2], omadd = scal[3];

    // ---- state mods ----
    float psum = 0.f;
#pragma unroll
    for (int m = 0; m < 4; ++m)
#pragma unroll
      for (int r = 0; r < 4; ++r) psum += th[m][r];
    psum += __shfl_xor(psum, 16); psum += __shfl_xor(psum, 32);
    const float mean = psum * (1.f / 60.f);
    if (coef != 0.f) {
#pragma unroll
      for (int m = 0; m < 4; ++m)
#pragma unroll
        for (int r = 0; r < 4; ++r) {
          const int o = 16 * m + 4 * g + r;
          if (o < 60) th[m][r] += coef * __sinf(mean - th[m][r]);
        }
    }
    if (dm != 0.f) {
      const float f = 0.05f * (1.f - chcol);
#pragma unroll
      for (int m = 0; m < 4; ++m) {
        if (m == 3 && g == 3) continue;
        const float4 n4 = *(const float4*)(p.noise + (size_t)l * 491520 + (size_t)b * 60 + 16 * m + 4 * g);
        const float na[4] = {n4.x, n4.y, n4.z, n4.w};
#pragma unroll
        for (int r = 0; r < 4; ++r) th[m][r] = fmaf(f, na[r], th[m][r]);
      }
    }
    float om[4][4];
#pragma unroll
    for (int m = 0; m < 4; ++m) {
      float4 o4;
      if (m == 3 && g == 3) o4 = make_float4(0.f, 0.f, 0.f, 0.f);
      else o4 = *(const float4*)(p.omega + l * 60 + 16 * m + 4 * g);
      const float oa[4] = {o4.x, o4.y, o4.z, o4.w};
#pragma unroll
      for (int r = 0; r < 4; ++r) {
        const int o = 16 * m + 4 * g + r;
        om[m][r] = (o < 60) ? 0.1f * (oa[r] + omadd) : 0.f;
        s[m][r] = __sinf(th[m][r]);
        cc[m][r] = __cosf(th[m][r]);
      }
    }

    // ---- A fragments from K[l] (f32 -> bf16, zero-padded) ----
    bf16x8v Af[4][2];
#pragma unroll
    for (int m = 0; m < 4; ++m) {
      const int i = 16 * m + c;
#pragma unroll
      for (int kt2 = 0; kt2 < 2; ++kt2) {
        u32x4v t;
        if (i < 60) {
          const float* kp = p.K + l * 3600 + i * 60 + 32 * kt2 + 8 * g;
          const float4 u0 = *(const float4*)(kp);
          float4 u1;
          if (kt2 == 1 && g == 3) u1 = make_float4(0.f, 0.f, 0.f, 0.f);
          else u1 = *(const float4*)(kp + 4);
          t[0] = pkbf(u0.x, u0.y); t[1] = pkbf(u0.z, u0.w);
          t[2] = pkbf(u1.x, u1.y); t[3] = pkbf(u1.z, u1.w);
        } else {
          t[0] = 0u; t[1] = 0u; t[2] = 0u; t[3] = 0u;
        }
        Af[m][kt2] = __builtin_bit_cast(bf16x8v, t);
      }
    }

    // ---- 10 Kuramoto steps ----
    for (int step = 0; step < 10; ++step) {
      unsigned sd[4][2], cd[4][2];
#pragma unroll
      for (int m = 0; m < 4; ++m) {
        sd[m][0] = pkbf(s[m][0], s[m][1]);  sd[m][1] = pkbf(s[m][2], s[m][3]);
        cd[m][0] = pkbf(cc[m][0], cc[m][1]); cd[m][1] = pkbf(cc[m][2], cc[m][3]);
      }
      bf16x8v BS0, BS1, BC0, BC1;
      ASM_FRAG(BS0, sd, 0, 1); ASM_FRAG(BS1, sd, 2, 3);
      ASM_FRAG(BC0, cd, 0, 1); ASM_FRAG(BC1, cd, 2, 3);
      const f32x4v z4 = {0.f, 0.f, 0.f, 0.f};
      f32x4v P[4], Q[4];
#pragma unroll
      for (int m = 0; m < 4; ++m) {
        f32x4v t0 = __builtin_amdgcn_mfma_f32_16x16x32_bf16(Af[m][0], BS0, z4, 0, 0, 0);
        P[m] = __builtin_amdgcn_mfma_f32_16x16x32_bf16(Af[m][1], BS1, t0, 0, 0, 0);
        f32x4v t1 = __builtin_amdgcn_mfma_f32_16x16x32_bf16(Af[m][0], BC0, z4, 0, 0, 0);
        Q[m] = __builtin_amdgcn_mfma_f32_16x16x32_bf16(Af[m][1], BC1, t1, 0, 0, 0);
      }
#pragma unroll
      for (int m = 0; m < 4; ++m)
#pragma unroll
        for (int r = 0; r < 4; ++r) {
          const float csum = cc[m][r] * P[m][r] - s[m][r] * Q[m][r];
          const float d = fmaf(ktot, csum, om[m][r]);
          th[m][r] += d;
          const float d2 = d * d;
          const float sdl = d * (1.f - d2 * (1.f / 6.f));
          const float cdl = 1.f - d2 * 0.5f;
          const float sn = s[m][r] * cdl + cc[m][r] * sdl;
          cc[m][r] = cc[m][r] * cdl - s[m][r] * sdl;
          s[m][r] = sn;
        }
    }

    // ---- epilogue: wrap theta, coherence, z-partial, publish ----
    float pc2 = 0.f, ps2 = 0.f;
#pragma unroll
    for (int m = 0; m < 4; ++m)
#pragma unroll
      for (int r = 0; r < 4; ++r) {
        th[m][r] = fmaf(-TWO_PI_F, rintf(th[m][r] * INV_2PI_F), th[m][r]);
        pc2 += cc[m][r]; ps2 += s[m][r];
      }
    pc2 += __shfl_xor(pc2, 16); pc2 += __shfl_xor(pc2, 32);
    ps2 += __shfl_xor(ps2, 16); ps2 += __shfl_xor(ps2, 32);
    const float mc2 = (pc2 - 4.f) * (1.f / 60.f);
    const float ms2 = ps2 * (1.f / 60.f);
    chcol = sqrtf(mc2 * mc2 + ms2 * ms2);
    if (l < 3) {
      const float tot = wave_sum(chcol) * 0.25f;
      if (lane == 0) redz[w] = tot;
      __syncthreads();
      if (tid == 0) p.part[(l + 1) * 256 + bid] = redz[0] + redz[1];
      if (bid == 0 && w == 0 && c == 0) {
        float* row0n = p.row0 + 64 * ((l + 1) & 1);
#pragma unroll
        for (int m = 0; m < 4; ++m)
#pragma unroll
          for (int r = 0; r < 4; ++r) {
            const int o = 16 * m + 4 * g + r;
            if (o < 60) row0n[o] = cc[m][r];
          }
      }
      if (bid == 0 && tid == 0) p.coh0[(l + 1) & 1] = chcol;
      gridg.sync();
    }
  }

  // ---- output: out = ([cos,sin] @ W_out + b_out) * coh ----
  {
    unsigned sd[4][2], cd[4][2];
#pragma unroll
    for (int m = 0; m < 4; ++m) {
      sd[m][0] = pkbf(s[m][0], s[m][1]);  sd[m][1] = pkbf(s[m][2], s[m][3]);
      cd[m][0] = pkbf(cc[m][0], cc[m][1]); cd[m][1] = pkbf(cc[m][2], cc[m][3]);
    }
    bf16x8v BS0, BS1, BC0, BC1;
    ASM_FRAG(BS0, sd, 0, 1); ASM_FRAG(BS1, sd, 2, 3);
    ASM_FRAG(BC0, cd, 0, 1); ASM_FRAG(BC1, cd, 2, 3);
    const f32x4v z4 = {0.f, 0.f, 0.f, 0.f};
#pragma unroll
    for (int mp = 0; mp < 16; ++mp) {
      const unsigned short* ap = p.Aout + (16 * mp + c) * 128 + 8 * g;
      const bf16x8v A0 = *(const bf16x8v*)(ap);
      const bf16x8v A1 = *(const bf16x8v*)(ap + 32);
      const bf16x8v A2 = *(const bf16x8v*)(ap + 64);
      const bf16x8v A3 = *(const bf16x8v*)(ap + 96);
      f32x4v d = __builtin_amdgcn_mfma_f32_16x16x32_bf16(A0, BC0, z4, 0, 0, 0);
      d = __builtin_amdgcn_mfma_f32_16x16x32_bf16(A1, BC1, d, 0, 0, 0);
      d = __builtin_amdgcn_mfma_f32_16x16x32_bf16(A2, BS0, d, 0, 0, 0);
      d = __builtin_amdgcn_mfma_f32_16x16x32_bf16(A3, BS1, d, 0, 0, 0);
      const float4 bo = *(const float4*)(p.b_out + 16 * mp + 4 * g);
      *(float4*)(&trans[w][c][16 * mp + 4 * g]) =
          make_float4((d[0] + bo.x) * chcol, (d[1] + bo.y) * chcol,
                      (d[2] + bo.z) * chcol, (d[3] + bo.w) * chcol);
    }
    __syncthreads();
#pragma unroll
    for (int row = 0; row < 16; ++row) {
      const float4 v = *(const float4*)(&trans[w][row][4 * lane]);
      *(float4*)(p.out + (size_t)(bid * 32 + w * 16 + row) * 256 + 4 * lane) = v;
    }
  }
}

// ---------------------------------------------------------------------------
// Workspace (bytes): Aenc @0 (64KB), Aout @65536 (64KB), part @131072 (4KB),
// row0 @135168 (2x64 f), coh0 @135680 (2 f). ~133 KB total.
// ---------------------------------------------------------------------------
extern "C" void kernel_launch(void* const* d_in, const int* in_sizes, int n_in,
                              void* d_out, int out_size, void* d_ws, size_t ws_size,
                              hipStream_t stream) {
  char* wsb = (char*)d_ws;
  Params h;
  h.x     = (const float*)d_in[0];
  h.W_enc = (const float*)d_in[1];
  h.b_enc = (const float*)d_in[2];
  h.K     = (const float*)d_in[3];
  h.omega = (const float*)d_in[4];
  h.Kglob = (const float*)d_in[5];
  h.aplK  = (const float*)d_in[6];
  h.aplOm = (const float*)d_in[7];
  h.W1    = (const float*)d_in[8];
  h.b1    = (const float*)d_in[9];
  h.W2    = (const float*)d_in[10];
  h.b2    = (const float*)d_in[11];
  h.W3    = (const float*)d_in[12];
  h.b3    = (const float*)d_in[13];
  h.prior = (const float*)d_in[14];
  h.noise = (const float*)d_in[15];
  h.W_out = (const float*)d_in[16];
  h.b_out = (const float*)d_in[17];
  h.Aenc  = (unsigned short*)wsb;
  h.Aout  = (unsigned short*)(wsb + 65536);
  h.part  = (float*)(wsb + 131072);
  h.row0  = (float*)(wsb + 135168);
  h.coh0  = (float*)(wsb + 135680);
  h.out   = (float*)d_out;

  void* args[] = {&h};
  hipLaunchCooperativeKernel((const void*)fused_net, dim3(256), dim3(128),
                             args, 0, stream);
}

// Round 6
// 104.538 us; speedup vs baseline: 2.2205x; 2.2205x over previous
//
#include <hip/hip_runtime.h>
#include <hip/hip_bf16.h>
#include <math.h>

typedef __attribute__((ext_vector_type(8))) short bf16x8v;
typedef __attribute__((ext_vector_type(4))) float f32x4v;
typedef __attribute__((ext_vector_type(4))) unsigned u32x4v;

namespace {

constexpr float PI_F      = 3.14159265358979323846f;
constexpr float TWO_PI_F  = 6.28318530717958647692f;
constexpr float INV_2PI_F = 0.15915494309189533577f;
constexpr float ZC_F      = 0.86602540378443864676f;

__device__ __constant__ float d_BOUNDS[8] = {0.1f, 0.2f, 0.4f, 0.6f, 0.75f,
                                             0.8660254037844386f, 0.92f, 0.97f};
__device__ __constant__ float d_PARITY[6] = {1.f, -1.f, 1.f, 1.f, -1.f, -1.f};
__device__ __constant__ int d_LEGAL[9][6] = {
    {0, 0, 0, 1, 1, 1},
    {1, 0, 1, 0, 1, 1},
    {1, 1, 1, 0, 1, 1},
    {0, 1, 0, 1, 1, 1},
    {1, 1, 1, 1, 1, 1},
    {0, 1, 0, 1, 1, 1},
    {0, 1, 0, 1, 0, 0},
    {0, 1, 1, 1, 0, 0},
    {0, 1, 1, 1, 0, 0}};

__device__ __forceinline__ float wave_sum(float v) {
#pragma unroll
  for (int o = 32; o > 0; o >>= 1) v += __shfl_xor(v, o, 64);
  return v;
}

__device__ __forceinline__ float gelu_exact(float x) {
  return 0.5f * x * (1.0f + erff(x * 0.70710678118654752440f));
}

__device__ __forceinline__ unsigned short f2b(float v) {
  return __builtin_bit_cast(unsigned short, __float2bfloat16(v));
}

__device__ __forceinline__ unsigned pkbf(float a, float b) {
  return ((unsigned)f2b(b) << 16) | (unsigned)f2b(a);
}

}  // namespace

// D-layout -> B-frag redistribution (verified rounds 3-5).
#define ASM_FRAG(dst, arr, m0, m1)                                     \
  {                                                                    \
    const unsigned q0 = (unsigned)__shfl((int)arr[m0][0], srcA, 64);   \
    const unsigned q1 = (unsigned)__shfl((int)arr[m1][0], srcA, 64);   \
    const unsigned q2 = (unsigned)__shfl((int)arr[m0][1], srcA, 64);   \
    const unsigned q3 = (unsigned)__shfl((int)arr[m1][1], srcA, 64);   \
    const unsigned q4 = (unsigned)__shfl((int)arr[m0][0], srcB, 64);   \
    const unsigned q5 = (unsigned)__shfl((int)arr[m1][0], srcB, 64);   \
    const unsigned q6 = (unsigned)__shfl((int)arr[m0][1], srcB, 64);   \
    const unsigned q7 = (unsigned)__shfl((int)arr[m1][1], srcB, 64);   \
    u32x4v tq;                                                         \
    tq[0] = hi ? q1 : q0;                                              \
    tq[1] = hi ? q3 : q2;                                              \
    tq[2] = hi ? q5 : q4;                                              \
    tq[3] = hi ? q7 : q6;                                              \
    dst = __builtin_bit_cast(bf16x8v, tq);                             \
  }

// ---------------------------------------------------------------------------
// Encoder: theta = pi*tanh(x @ W_enc + b_enc), per-block coh partial sums.
// 512 blocks x 1024 thr (16 waves, 1 row/wave), W_enc staged in LDS.
// Blocks 0..15 additionally convert K -> padded bf16 [4][64][64] (ktot is
// folded post-MFMA in kura, so fragments are decision-independent).
// ---------------------------------------------------------------------------
__global__ __launch_bounds__(1024) void enc_kernel(
    const float* __restrict__ x, const float* __restrict__ W_enc,
    const float* __restrict__ b_enc, const float* __restrict__ K,
    float* __restrict__ theta, float* __restrict__ part,
    unsigned short* __restrict__ Kb) {
  __shared__ float Wt[128 * 60];
  __shared__ float red[16];
  const int tid = threadIdx.x;
  const int wave = tid >> 6, lane = tid & 63;
  const int r = __builtin_amdgcn_readfirstlane(blockIdx.x * 16 + wave);
  float acc = 0.f;
  for (int kt = 0; kt < 4; ++kt) {
    __syncthreads();
    for (int t = tid; t < 7680; t += 1024) Wt[t] = W_enc[kt * 7680 + t];
    __syncthreads();
    const float* xr = x + r * 512 + kt * 128;
    if (lane < 60) {
#pragma unroll 8
      for (int kk = 0; kk < 128; ++kk) acc = fmaf(xr[kk], Wt[kk * 60 + lane], acc);
    }
  }
  float th = 0.f, c = 0.f, s = 0.f;
  if (lane < 60) {
    th = PI_F * tanhf(acc + b_enc[lane]);
    theta[r * 60 + lane] = th;
    c = __cosf(th);
    s = __sinf(th);
  }
  const float mc = wave_sum(c) * (1.f / 60.f);
  const float ms = wave_sum(s) * (1.f / 60.f);
  const float ch = sqrtf(mc * mc + ms * ms);
  if (lane == 0) red[wave] = ch;
  __syncthreads();
  if (tid == 0) {
    float t0 = 0.f;
#pragma unroll
    for (int w = 0; w < 16; ++w) t0 += red[w];
    part[blockIdx.x] = t0;
  }
  // K -> bf16 padded (16 blocks x 1024 elems = 4*64*64)
  if (blockIdx.x < 16) {
    const int t = blockIdx.x * 1024 + tid;
    const int l = t >> 12, rem = t & 4095, i = rem >> 6, k = rem & 63;
    Kb[t] = f2b((i < 60 && k < 60) ? K[l * 3600 + i * 60 + k] : 0.f);
  }
}

// ---------------------------------------------------------------------------
// Fused decide + MFMA Kuramoto. 512 blocks x 64 thr (1 wave = 16 batch cols).
// Decide is redundant per block (z from 512 part entries, row-0 MLP).
// State in D-fragment layout (col=lane&15=batch, row=16m+4g+r=osc); B-frags
// via ASM_FRAG shuffles; per-step s/c by __sinf/__cosf of unwrapped theta;
// ktot folded post-MFMA so A-frags = raw bf16 K.
// ---------------------------------------------------------------------------
__global__ __launch_bounds__(64, 2) void kura_mfma(
    float* __restrict__ theta, const float* __restrict__ noiseL,
    const unsigned short* __restrict__ Kb, const float* __restrict__ omega,
    const float* __restrict__ Kglob, const float* __restrict__ aplK,
    const float* __restrict__ aplOm,
    const float* __restrict__ W1, const float* __restrict__ b1,
    const float* __restrict__ W2, const float* __restrict__ b2,
    const float* __restrict__ W3, const float* __restrict__ b3,
    const float* __restrict__ prior,
    float* __restrict__ part, float* __restrict__ coh, int l) {
  __shared__ float fe[64], hh[64], lgits[8];
  const int tid = threadIdx.x;
  const int c = tid & 15, g = tid >> 4;
  const bool hi = g >= 2;
  const int b = blockIdx.x * 16 + c;
  const int srcA = ((2 * g) & 3) * 16 + c;
  const int srcB = srcA + 16;

  // ---- decide: z from partials ----
  const float4 p0 = *(const float4*)(part + l * 512 + 8 * tid);
  const float4 p1 = *(const float4*)(part + l * 512 + 8 * tid + 4);
  const float z =
      wave_sum(p0.x + p0.y + p0.z + p0.w + p1.x + p1.y + p1.z + p1.w) *
      (1.f / 8192.f);
  int tier = 0;
#pragma unroll
  for (int i = 0; i < 8; ++i) tier += (z >= d_BOUNDS[i]) ? 1 : 0;
  const float dsneg = expf(-36.f * (z - ZC_F) * (z - ZC_F));
  // row-0 feats + coherence
  const float th0 = (tid < 60) ? theta[tid] : 0.f;
  const float c00 = __cosf(th0);
  const float pc0 = wave_sum((tid < 60) ? c00 : 0.f) * (1.f / 60.f);
  const float ps0 = wave_sum((tid < 60) ? __sinf(th0) : 0.f) * (1.f / 60.f);
  const float ch0 = sqrtf(pc0 * pc0 + ps0 * ps0);
  fe[tid] = (tid < 60) ? c00
          : (tid == 60) ? z
          : (tid == 61) ? ch0
          : (tid == 62) ? dsneg
                        : (float)(tier + 1) * (1.f / 9.f);
  __syncthreads();
  float a1 = b1[l * 64 + tid];
#pragma unroll 8
  for (int k = 0; k < 64; ++k) a1 = fmaf(fe[k], W1[l * 4096 + k * 64 + tid], a1);
  hh[tid] = gelu_exact(a1);
  __syncthreads();
  float a2 = b2[l * 64 + tid];
#pragma unroll 8
  for (int k = 0; k < 64; ++k) a2 = fmaf(hh[k], W2[l * 4096 + k * 64 + tid], a2);
  __syncthreads();
  fe[tid] = gelu_exact(a2);
  __syncthreads();
  if (tid < 6) {
    float a3 = b3[l * 6 + tid] + prior[l * 6 + tid];
#pragma unroll 8
    for (int k = 0; k < 64; ++k) a3 = fmaf(fe[k], W3[l * 384 + k * 6 + tid], a3);
    lgits[tid] = a3;
  }
  __syncthreads();
  int idx = 0;
  float best = -INFINITY;
#pragma unroll
  for (int m2 = 0; m2 < 6; ++m2)
    if (d_LEGAL[tier][m2] && lgits[m2] > best) { best = lgits[m2]; idx = m2; }
  const float par = d_PARITY[idx];
  const float coef = (idx == 1) ? 0.1f : ((idx == 5) ? -0.1f : 0.f);
  const bool dm = (idx == 4);
  const float ktot =
      (1.f + par * (aplK[l * 6 + idx] * z) * 0.5f) * 0.1f * Kglob[l] * (1.f / 60.f);
  const float omadd = aplOm[l * 6 + idx] * par;

  // ---- state load (D-layout) ----
  float th[4][4], om[4][4];
#pragma unroll
  for (int m = 0; m < 4; ++m) {
    if (m == 3 && g == 3) {
#pragma unroll
      for (int r = 0; r < 4; ++r) { th[m][r] = 0.f; om[m][r] = 0.f; }
    } else {
      const float4 t4 = *(const float4*)(theta + b * 60 + 16 * m + 4 * g);
      const float4 o4 = *(const float4*)(omega + l * 60 + 16 * m + 4 * g);
      const float ta[4] = {t4.x, t4.y, t4.z, t4.w};
      const float oa[4] = {o4.x, o4.y, o4.z, o4.w};
#pragma unroll
      for (int r = 0; r < 4; ++r) { th[m][r] = ta[r]; om[m][r] = 0.1f * (oa[r] + omadd); }
    }
  }
  // entry coherence + mean (pads are 0 -> cos pad = 1, subtract 4)
  float pcc = 0.f, pss = 0.f, psum = 0.f;
#pragma unroll
  for (int m = 0; m < 4; ++m)
#pragma unroll
    for (int r = 0; r < 4; ++r) {
      pcc += __cosf(th[m][r]);
      pss += __sinf(th[m][r]);
      psum += th[m][r];
    }
  pcc += __shfl_xor(pcc, 16); pcc += __shfl_xor(pcc, 32);
  pss += __shfl_xor(pss, 16); pss += __shfl_xor(pss, 32);
  psum += __shfl_xor(psum, 16); psum += __shfl_xor(psum, 32);
  const float mcp = (pcc - 4.f) * (1.f / 60.f);
  const float msp = pss * (1.f / 60.f);
  const float ch_pre = sqrtf(mcp * mcp + msp * msp);
  const float mean = psum * (1.f / 60.f);
  if (coef != 0.f) {
#pragma unroll
    for (int m = 0; m < 4; ++m)
#pragma unroll
      for (int r = 0; r < 4; ++r) {
        const int o = 16 * m + 4 * g + r;
        if (o < 60) th[m][r] += coef * __sinf(mean - th[m][r]);
      }
  }
  if (dm) {
    const float f = 0.05f * (1.f - ch_pre);
#pragma unroll
    for (int m = 0; m < 4; ++m) {
      if (m == 3 && g == 3) continue;
      const float4 n4 = *(const float4*)(noiseL + (size_t)b * 60 + 16 * m + 4 * g);
      const float na[4] = {n4.x, n4.y, n4.z, n4.w};
#pragma unroll
      for (int r = 0; r < 4; ++r) th[m][r] = fmaf(f, na[r], th[m][r]);
    }
  }
  float s[4][4], cc[4][4];
#pragma unroll
  for (int m = 0; m < 4; ++m)
#pragma unroll
    for (int r = 0; r < 4; ++r) { s[m][r] = __sinf(th[m][r]); cc[m][r] = __cosf(th[m][r]); }

  // ---- A fragments: raw bf16 K rows (padded) ----
  bf16x8v Af[4][2];
#pragma unroll
  for (int m = 0; m < 4; ++m)
#pragma unroll
    for (int kt = 0; kt < 2; ++kt)
      Af[m][kt] = *(const bf16x8v*)(Kb + l * 4096 + (16 * m + c) * 64 + 32 * kt + 8 * g);

  // ---- 10 steps ----
  for (int step = 0; step < 10; ++step) {
    unsigned sd[4][2], cd[4][2];
#pragma unroll
    for (int m = 0; m < 4; ++m) {
      sd[m][0] = pkbf(s[m][0], s[m][1]);  sd[m][1] = pkbf(s[m][2], s[m][3]);
      cd[m][0] = pkbf(cc[m][0], cc[m][1]); cd[m][1] = pkbf(cc[m][2], cc[m][3]);
    }
    bf16x8v BS0, BS1, BC0, BC1;
    ASM_FRAG(BS0, sd, 0, 1); ASM_FRAG(BS1, sd, 2, 3);
    ASM_FRAG(BC0, cd, 0, 1); ASM_FRAG(BC1, cd, 2, 3);
    const f32x4v z4 = {0.f, 0.f, 0.f, 0.f};
    f32x4v P[4], Q[4];
#pragma unroll
    for (int m = 0; m < 4; ++m) {
      f32x4v t0 = __builtin_amdgcn_mfma_f32_16x16x32_bf16(Af[m][0], BS0, z4, 0, 0, 0);
      P[m] = __builtin_amdgcn_mfma_f32_16x16x32_bf16(Af[m][1], BS1, t0, 0, 0, 0);
      f32x4v t1 = __builtin_amdgcn_mfma_f32_16x16x32_bf16(Af[m][0], BC0, z4, 0, 0, 0);
      Q[m] = __builtin_amdgcn_mfma_f32_16x16x32_bf16(Af[m][1], BC1, t1, 0, 0, 0);
    }
#pragma unroll
    for (int m = 0; m < 4; ++m)
#pragma unroll
      for (int r = 0; r < 4; ++r) {
        const float csum = cc[m][r] * P[m][r] - s[m][r] * Q[m][r];
        const float d = fmaf(ktot, csum, om[m][r]);
        th[m][r] += d;
        s[m][r] = __sinf(th[m][r]);
        cc[m][r] = __cosf(th[m][r]);
      }
  }

  // ---- epilogue ----
  float pc2 = 0.f, ps2 = 0.f;
#pragma unroll
  for (int m = 0; m < 4; ++m)
#pragma unroll
    for (int r = 0; r < 4; ++r) { pc2 += cc[m][r]; ps2 += s[m][r]; }
  pc2 += __shfl_xor(pc2, 16); pc2 += __shfl_xor(pc2, 32);
  ps2 += __shfl_xor(ps2, 16); ps2 += __shfl_xor(ps2, 32);
  const float mc2 = (pc2 - 4.f) * (1.f / 60.f);
  const float ms2 = ps2 * (1.f / 60.f);
  const float ch = sqrtf(mc2 * mc2 + ms2 * ms2);
#pragma unroll
  for (int m = 0; m < 4; ++m) {
    if (m == 3 && g == 3) continue;
    float wv[4];
#pragma unroll
    for (int r = 0; r < 4; ++r) {
      const float t = th[m][r];
      wv[r] = fmaf(-TWO_PI_F, rintf(t * INV_2PI_F), t);
    }
    *(float4*)(theta + b * 60 + 16 * m + 4 * g) =
        make_float4(wv[0], wv[1], wv[2], wv[3]);
  }
  if (tid < 16) coh[b] = ch;
  if (l < 3) {
    const float tot = wave_sum(ch) * 0.25f;  // each col counted 4x over g
    if (tid == 0) part[(l + 1) * 512 + blockIdx.x] = tot;
  }
}

// ---------------------------------------------------------------------------
// Output: out = ([cos th, sin th] @ W_out + b_out) * coh  (f32).
// 512 blocks x 256 thr; 16 rows staged as cos/sin in LDS; thread d owns col d.
// ---------------------------------------------------------------------------
__global__ __launch_bounds__(256) void out_kernel(
    const float* __restrict__ theta, const float* __restrict__ coh,
    const float* __restrict__ W_out, const float* __restrict__ b_out,
    float* __restrict__ out) {
  __shared__ __align__(16) float sc[16][120];
  __shared__ float cohl[16];
  const int tid = threadIdx.x;
  const int b0 = blockIdx.x * 16;
  for (int t = tid; t < 960; t += 256) {
    const int r = t / 60, n = t % 60;
    const float th = theta[(b0 + r) * 60 + n];
    sc[r][n] = __cosf(th);
    sc[r][60 + n] = __sinf(th);
  }
  if (tid < 16) cohl[tid] = coh[b0 + tid];
  __syncthreads();
  float acc[16];
#pragma unroll
  for (int r = 0; r < 16; ++r) acc[r] = 0.f;
  const int d = tid;
  for (int t = 0; t < 30; ++t) {
    const float w0 = W_out[(4 * t + 0) * 256 + d];
    const float w1 = W_out[(4 * t + 1) * 256 + d];
    const float w2 = W_out[(4 * t + 2) * 256 + d];
    const float w3 = W_out[(4 * t + 3) * 256 + d];
#pragma unroll
    for (int r = 0; r < 16; ++r) {
      const float4 p = *reinterpret_cast<const float4*>(&sc[r][4 * t]);
      acc[r] = fmaf(p.w, w3, fmaf(p.z, w2, fmaf(p.y, w1, fmaf(p.x, w0, acc[r]))));
    }
  }
  const float bo = b_out[d];
#pragma unroll
  for (int r = 0; r < 16; ++r)
    out[(size_t)(b0 + r) * 256 + d] = (acc[r] + bo) * cohl[r];
}

// ---------------------------------------------------------------------------
// Workspace (float offsets): theta [491520] @0, part [4*512] @491520,
// coh [8192] @493568, Kb [16384 ushort] @501760. Total ~2.04 MB.
// ---------------------------------------------------------------------------
extern "C" void kernel_launch(void* const* d_in, const int* in_sizes, int n_in,
                              void* d_out, int out_size, void* d_ws, size_t ws_size,
                              hipStream_t stream) {
  const float* x     = (const float*)d_in[0];
  const float* W_enc = (const float*)d_in[1];
  const float* b_enc = (const float*)d_in[2];
  const float* K     = (const float*)d_in[3];
  const float* omega = (const float*)d_in[4];
  const float* Kglob = (const float*)d_in[5];
  const float* aplK  = (const float*)d_in[6];
  const float* aplOm = (const float*)d_in[7];
  const float* W1    = (const float*)d_in[8];
  const float* b1    = (const float*)d_in[9];
  const float* W2    = (const float*)d_in[10];
  const float* b2    = (const float*)d_in[11];
  const float* W3    = (const float*)d_in[12];
  const float* b3    = (const float*)d_in[13];
  const float* prior = (const float*)d_in[14];
  const float* noise = (const float*)d_in[15];
  const float* W_out = (const float*)d_in[16];
  const float* b_out = (const float*)d_in[17];

  float* ws    = (float*)d_ws;
  float* theta = ws;
  float* part  = ws + 491520;
  float* coh   = ws + 493568;
  unsigned short* Kb = (unsigned short*)(ws + 501760);

  enc_kernel<<<512, 1024, 0, stream>>>(x, W_enc, b_enc, K, theta, part, Kb);
  for (int l = 0; l < 4; ++l) {
    kura_mfma<<<512, 64, 0, stream>>>(theta, noise + (size_t)l * 491520,
                                      Kb, omega, Kglob, aplK, aplOm,
                                      W1, b1, W2, b2, W3, b3, prior,
                                      part, coh, l);
  }
  out_kernel<<<512, 256, 0, stream>>>(theta, coh, W_out, b_out, (float*)d_out);
}

// Round 7
// 81.295 us; speedup vs baseline: 2.8553x; 1.2859x over previous
//
#include <hip/hip_runtime.h>
#include <hip/hip_bf16.h>
#include <math.h>

typedef __attribute__((ext_vector_type(8))) short bf16x8v;
typedef __attribute__((ext_vector_type(4))) float f32x4v;
typedef __attribute__((ext_vector_type(4))) unsigned u32x4v;

namespace {

constexpr float PI_F      = 3.14159265358979323846f;
constexpr float TWO_PI_F  = 6.28318530717958647692f;
constexpr float INV_2PI_F = 0.15915494309189533577f;
constexpr float ZC_F      = 0.86602540378443864676f;

__device__ __constant__ float d_BOUNDS[8] = {0.1f, 0.2f, 0.4f, 0.6f, 0.75f,
                                             0.8660254037844386f, 0.92f, 0.97f};
__device__ __constant__ float d_PARITY[6] = {1.f, -1.f, 1.f, 1.f, -1.f, -1.f};
__device__ __constant__ int d_LEGAL[9][6] = {
    {0, 0, 0, 1, 1, 1},
    {1, 0, 1, 0, 1, 1},
    {1, 1, 1, 0, 1, 1},
    {0, 1, 0, 1, 1, 1},
    {1, 1, 1, 1, 1, 1},
    {0, 1, 0, 1, 1, 1},
    {0, 1, 0, 1, 0, 0},
    {0, 1, 1, 1, 0, 0},
    {0, 1, 1, 1, 0, 0}};

__device__ __forceinline__ float wave_sum(float v) {
#pragma unroll
  for (int o = 32; o > 0; o >>= 1) v += __shfl_xor(v, o, 64);
  return v;
}

__device__ __forceinline__ float gelu_exact(float x) {
  return 0.5f * x * (1.0f + erff(x * 0.70710678118654752440f));
}

__device__ __forceinline__ unsigned short f2b(float v) {
  return __builtin_bit_cast(unsigned short, __float2bfloat16(v));
}

__device__ __forceinline__ unsigned pkbf(float a, float b) {
  return ((unsigned)f2b(b) << 16) | (unsigned)f2b(a);
}

}  // namespace

// LDS pair-array stride (dwords): 32 pairs + 4 pad -> 2-way bank alias (free).
#define LSTR 36

// ---------------------------------------------------------------------------
// Encoder: theta = pi*tanh(x @ W_enc + b_enc), per-block coh partials.
// 512 blocks x 1024 thr. Tail work: blocks 0..15 convert K -> bf16 padded
// [4][64][64]; blocks 16..47 convert W_out -> bf16 [256][128] (cos|sin).
// ---------------------------------------------------------------------------
__global__ __launch_bounds__(1024) void enc_kernel(
    const float* __restrict__ x, const float* __restrict__ W_enc,
    const float* __restrict__ b_enc, const float* __restrict__ K,
    const float* __restrict__ W_out, float* __restrict__ theta,
    float* __restrict__ part, unsigned short* __restrict__ Kb,
    unsigned short* __restrict__ Wob) {
  __shared__ float Wt[128 * 60];
  __shared__ float red[16];
  const int tid = threadIdx.x;
  const int wave = tid >> 6, lane = tid & 63;
  const int r = __builtin_amdgcn_readfirstlane(blockIdx.x * 16 + wave);
  float acc = 0.f;
  for (int kt = 0; kt < 4; ++kt) {
    __syncthreads();
    for (int t = tid; t < 7680; t += 1024) Wt[t] = W_enc[kt * 7680 + t];
    __syncthreads();
    const float* xr = x + r * 512 + kt * 128;
    if (lane < 60) {
#pragma unroll 8
      for (int kk = 0; kk < 128; ++kk) acc = fmaf(xr[kk], Wt[kk * 60 + lane], acc);
    }
  }
  float th = 0.f, c = 0.f, s = 0.f;
  if (lane < 60) {
    th = PI_F * tanhf(acc + b_enc[lane]);
    theta[r * 60 + lane] = th;
    c = __cosf(th);
    s = __sinf(th);
  }
  const float mc = wave_sum(c) * (1.f / 60.f);
  const float ms = wave_sum(s) * (1.f / 60.f);
  const float ch = sqrtf(mc * mc + ms * ms);
  if (lane == 0) red[wave] = ch;
  __syncthreads();
  if (tid == 0) {
    float t0 = 0.f;
#pragma unroll
    for (int w = 0; w < 16; ++w) t0 += red[w];
    part[blockIdx.x] = t0;
  }
  if (blockIdx.x < 16) {  // K -> bf16 padded [l][64][64]
    const int t = blockIdx.x * 1024 + tid;
    const int l = t >> 12, rem = t & 4095, i = rem >> 6, k = rem & 63;
    Kb[t] = f2b((i < 60 && k < 60) ? K[l * 3600 + i * 60 + k] : 0.f);
  } else if (blockIdx.x < 48) {  // W_out -> bf16 [d][128] (cos|sin k-halves)
    const int t = (blockIdx.x - 16) * 1024 + tid;
    const int d = t >> 7, kk = t & 127, prt = kk >> 6, o = kk & 63;
    Wob[t] = f2b((o < 60) ? W_out[(prt * 60 + o) * 256 + d] : 0.f);
  }
}

// ---------------------------------------------------------------------------
// Fused decide + Kuramoto (+output for l==3). 512 blocks x 256 thr (4 waves).
// Wave w owns osc tile m=w (16 rows); lane (c,g) holds rows 16w+4g+0..3 of
// batch col bid*16+c. Per step: waves publish sin/cos bf16 pairs to LDS
// ([col][pair] stride LSTR), barrier, each wave ds_read_b128 its B-frags,
// 4 MFMA, VALU update. l==3 additionally runs the out-GEMM from the final
// published LDS state and writes d_out (coalesced via LDS transpose).
// ---------------------------------------------------------------------------
__global__ __launch_bounds__(256, 2) void kura_mfma(
    float* __restrict__ theta, const float* __restrict__ noiseL,
    const unsigned short* __restrict__ Kb, const unsigned short* __restrict__ Wob,
    const float* __restrict__ omega, const float* __restrict__ Kglob,
    const float* __restrict__ aplK, const float* __restrict__ aplOm,
    const float* __restrict__ W1, const float* __restrict__ b1,
    const float* __restrict__ W2, const float* __restrict__ b2,
    const float* __restrict__ W3, const float* __restrict__ b3,
    const float* __restrict__ prior, const float* __restrict__ b_out,
    float* __restrict__ part, float* __restrict__ out, int l) {
  __shared__ float fe[64], hh[64], lgits[8], scal[4];
  __shared__ float redM[4][16][4];
  __shared__ unsigned sinL[16 * LSTR], cosL[16 * LSTR];
  __shared__ __align__(16) float trans[16][260];
  const int tid = threadIdx.x;
  const int w = tid >> 6;
  const int lane = tid & 63;
  const int c = lane & 15, g = lane >> 4;
  const int bid = blockIdx.x;
  const int b = bid * 16 + c;
  const bool pad = (w == 3) && (g == 3);

  // ---- decide: wave 0 computes z, feats, MLP; tid 0 publishes scalars ----
  float z = 0.f;
  int tier = 0;
  if (tid < 64) {
    const float4 p0 = *(const float4*)(part + l * 512 + 8 * tid);
    const float4 p1 = *(const float4*)(part + l * 512 + 8 * tid + 4);
    z = wave_sum(p0.x + p0.y + p0.z + p0.w + p1.x + p1.y + p1.z + p1.w) *
        (1.f / 8192.f);
#pragma unroll
    for (int i = 0; i < 8; ++i) tier += (z >= d_BOUNDS[i]) ? 1 : 0;
    const float dsneg = expf(-36.f * (z - ZC_F) * (z - ZC_F));
    const float th0 = (tid < 60) ? theta[tid] : 0.f;
    const float c00 = __cosf(th0);
    const float pc0 = wave_sum((tid < 60) ? c00 : 0.f) * (1.f / 60.f);
    const float ps0 = wave_sum((tid < 60) ? __sinf(th0) : 0.f) * (1.f / 60.f);
    const float ch0 = sqrtf(pc0 * pc0 + ps0 * ps0);
    fe[tid] = (tid < 60) ? c00
            : (tid == 60) ? z
            : (tid == 61) ? ch0
            : (tid == 62) ? dsneg
                          : (float)(tier + 1) * (1.f / 9.f);
  }
  __syncthreads();
  if (tid < 64) {
    float a1 = b1[l * 64 + tid];
#pragma unroll 8
    for (int k = 0; k < 64; ++k) a1 = fmaf(fe[k], W1[l * 4096 + k * 64 + tid], a1);
    hh[tid] = gelu_exact(a1);
  }
  __syncthreads();
  float a2 = 0.f;
  if (tid < 64) {
    a2 = b2[l * 64 + tid];
#pragma unroll 8
    for (int k = 0; k < 64; ++k) a2 = fmaf(hh[k], W2[l * 4096 + k * 64 + tid], a2);
  }
  __syncthreads();
  if (tid < 64) fe[tid] = gelu_exact(a2);
  __syncthreads();
  if (tid < 6) {
    float a3 = b3[l * 6 + tid] + prior[l * 6 + tid];
#pragma unroll 8
    for (int k = 0; k < 64; ++k) a3 = fmaf(fe[k], W3[l * 384 + k * 6 + tid], a3);
    lgits[tid] = a3;
  }
  __syncthreads();
  if (tid == 0) {
    int idx = 0;
    float best = -INFINITY;
#pragma unroll
    for (int m2 = 0; m2 < 6; ++m2)
      if (d_LEGAL[tier][m2] && lgits[m2] > best) { best = lgits[m2]; idx = m2; }
    const float par = d_PARITY[idx];
    scal[0] = (idx == 1) ? 0.1f : ((idx == 5) ? -0.1f : 0.f);
    scal[1] = (idx == 4) ? 1.f : 0.f;
    scal[2] = (1.f + par * (aplK[l * 6 + idx] * z) * 0.5f) * 0.1f * Kglob[l] * (1.f / 60.f);
    scal[3] = aplOm[l * 6 + idx] * par;
  }
  __syncthreads();
  const float coef = scal[0], dmn = scal[1], ktot = scal[2], omadd = scal[3];

  // ---- state load: 4 osc/lane (rows 16w+4g+0..3) ----
  float th[4], s4[4], c4[4], om4[4];
  if (!pad) {
    const float4 t4 = *(const float4*)(theta + b * 60 + 16 * w + 4 * g);
    const float4 o4 = *(const float4*)(omega + l * 60 + 16 * w + 4 * g);
    th[0] = t4.x; th[1] = t4.y; th[2] = t4.z; th[3] = t4.w;
    om4[0] = 0.1f * (o4.x + omadd); om4[1] = 0.1f * (o4.y + omadd);
    om4[2] = 0.1f * (o4.z + omadd); om4[3] = 0.1f * (o4.w + omadd);
  } else {
#pragma unroll
    for (int r = 0; r < 4; ++r) { th[r] = 0.f; om4[r] = 0.f; }
  }

  // ---- entry coherence + mean per col (cross-wave via LDS) ----
  float psum = 0.f, pcc = 0.f, pss = 0.f;
#pragma unroll
  for (int r = 0; r < 4; ++r) {
    psum += th[r];
    pcc += __cosf(th[r]);
    pss += __sinf(th[r]);
  }
  psum += __shfl_xor(psum, 16); psum += __shfl_xor(psum, 32);
  pcc += __shfl_xor(pcc, 16);  pcc += __shfl_xor(pcc, 32);
  pss += __shfl_xor(pss, 16);  pss += __shfl_xor(pss, 32);
  redM[w][c][0] = psum; redM[w][c][1] = pcc; redM[w][c][2] = pss;
  __syncthreads();
  {
    float tsum = 0.f, tc = 0.f, ts = 0.f;
#pragma unroll
    for (int ww = 0; ww < 4; ++ww) {
      tsum += redM[ww][c][0]; tc += redM[ww][c][1]; ts += redM[ww][c][2];
    }
    const float mean = tsum * (1.f / 60.f);
    const float mcp = (tc - 4.f) * (1.f / 60.f);
    const float msp = ts * (1.f / 60.f);
    const float ch_pre = sqrtf(mcp * mcp + msp * msp);
    if (coef != 0.f) {
#pragma unroll
      for (int r = 0; r < 4; ++r)
        if (!pad) th[r] += coef * __sinf(mean - th[r]);
    }
    if (dmn != 0.f && !pad) {
      const float f = 0.05f * (1.f - ch_pre);
      const float4 n4 = *(const float4*)(noiseL + (size_t)b * 60 + 16 * w + 4 * g);
      th[0] = fmaf(f, n4.x, th[0]); th[1] = fmaf(f, n4.y, th[1]);
      th[2] = fmaf(f, n4.z, th[2]); th[3] = fmaf(f, n4.w, th[3]);
    }
  }
#pragma unroll
  for (int r = 0; r < 4; ++r) { s4[r] = __sinf(th[r]); c4[r] = __cosf(th[r]); }

  // ---- A fragments: rows 16w+c of padded bf16 K ----
  const bf16x8v Af0 = *(const bf16x8v*)(Kb + l * 4096 + (16 * w + c) * 64 + 8 * g);
  const bf16x8v Af1 = *(const bf16x8v*)(Kb + l * 4096 + (16 * w + c) * 64 + 32 + 8 * g);

  const int wr = c * LSTR + 8 * w + 2 * g;  // write slot (pair index)
  const f32x4v z4 = {0.f, 0.f, 0.f, 0.f};

  // ---- 10 steps ----
  for (int step = 0; step < 10; ++step) {
    *(uint2*)&sinL[wr] = make_uint2(pkbf(s4[0], s4[1]), pkbf(s4[2], s4[3]));
    *(uint2*)&cosL[wr] = make_uint2(pkbf(c4[0], c4[1]), pkbf(c4[2], c4[3]));
    __syncthreads();
    const int rb = c * LSTR + 4 * g;
    const bf16x8v BS0 = __builtin_bit_cast(bf16x8v, *(const u32x4v*)&sinL[rb]);
    const bf16x8v BS1 = __builtin_bit_cast(bf16x8v, *(const u32x4v*)&sinL[rb + 16]);
    const bf16x8v BC0 = __builtin_bit_cast(bf16x8v, *(const u32x4v*)&cosL[rb]);
    const bf16x8v BC1 = __builtin_bit_cast(bf16x8v, *(const u32x4v*)&cosL[rb + 16]);
    f32x4v t0 = __builtin_amdgcn_mfma_f32_16x16x32_bf16(Af0, BS0, z4, 0, 0, 0);
    const f32x4v P = __builtin_amdgcn_mfma_f32_16x16x32_bf16(Af1, BS1, t0, 0, 0, 0);
    f32x4v t1 = __builtin_amdgcn_mfma_f32_16x16x32_bf16(Af0, BC0, z4, 0, 0, 0);
    const f32x4v Q = __builtin_amdgcn_mfma_f32_16x16x32_bf16(Af1, BC1, t1, 0, 0, 0);
#pragma unroll
    for (int r = 0; r < 4; ++r) {
      const float csum = c4[r] * P[r] - s4[r] * Q[r];
      const float d = fmaf(ktot, csum, om4[r]);
      th[r] += d;
      s4[r] = __sinf(th[r]);
      c4[r] = __cosf(th[r]);
    }
    __syncthreads();
  }

  // ---- epilogue: coherence per col ----
  float pc2 = 0.f, ps2 = 0.f;
#pragma unroll
  for (int r = 0; r < 4; ++r) { pc2 += c4[r]; ps2 += s4[r]; }
  pc2 += __shfl_xor(pc2, 16); pc2 += __shfl_xor(pc2, 32);
  ps2 += __shfl_xor(ps2, 16); ps2 += __shfl_xor(ps2, 32);
  redM[w][c][0] = pc2; redM[w][c][1] = ps2;
  __syncthreads();
  float tc2 = 0.f, ts2 = 0.f;
#pragma unroll
  for (int ww = 0; ww < 4; ++ww) { tc2 += redM[ww][c][0]; ts2 += redM[ww][c][1]; }
  const float mc2 = (tc2 - 4.f) * (1.f / 60.f);
  const float ms2 = ts2 * (1.f / 60.f);
  const float ch = sqrtf(mc2 * mc2 + ms2 * ms2);

  if (l < 3) {
    if (!pad) {
      float wv[4];
#pragma unroll
      for (int r = 0; r < 4; ++r)
        wv[r] = fmaf(-TWO_PI_F, rintf(th[r] * INV_2PI_F), th[r]);
      *(float4*)(theta + b * 60 + 16 * w + 4 * g) =
          make_float4(wv[0], wv[1], wv[2], wv[3]);
    }
    if (tid == 0) { /* placeholder */ }
    const float tot = wave_sum(ch) * 0.25f;  // wave 0: 16 cols, each x4 over g
    if (tid == 0) part[(l + 1) * 512 + bid] = tot;
    return;
  }

  // ---- l==3: output GEMM from final state ----
  *(uint2*)&sinL[wr] = make_uint2(pkbf(s4[0], s4[1]), pkbf(s4[2], s4[3]));
  *(uint2*)&cosL[wr] = make_uint2(pkbf(c4[0], c4[1]), pkbf(c4[2], c4[3]));
  __syncthreads();
  const int rb = c * LSTR + 4 * g;
  const bf16x8v BS0 = __builtin_bit_cast(bf16x8v, *(const u32x4v*)&sinL[rb]);
  const bf16x8v BS1 = __builtin_bit_cast(bf16x8v, *(const u32x4v*)&sinL[rb + 16]);
  const bf16x8v BC0 = __builtin_bit_cast(bf16x8v, *(const u32x4v*)&cosL[rb]);
  const bf16x8v BC1 = __builtin_bit_cast(bf16x8v, *(const u32x4v*)&cosL[rb + 16]);
#pragma unroll
  for (int i = 0; i < 4; ++i) {
    const int mp = 4 * w + i;
    const unsigned short* ap = Wob + (16 * mp + c) * 128 + 8 * g;
    const bf16x8v A0 = *(const bf16x8v*)(ap);
    const bf16x8v A1 = *(const bf16x8v*)(ap + 32);
    const bf16x8v A2 = *(const bf16x8v*)(ap + 64);
    const bf16x8v A3 = *(const bf16x8v*)(ap + 96);
    f32x4v d = __builtin_amdgcn_mfma_f32_16x16x32_bf16(A0, BC0, z4, 0, 0, 0);
    d = __builtin_amdgcn_mfma_f32_16x16x32_bf16(A1, BC1, d, 0, 0, 0);
    d = __builtin_amdgcn_mfma_f32_16x16x32_bf16(A2, BS0, d, 0, 0, 0);
    d = __builtin_amdgcn_mfma_f32_16x16x32_bf16(A3, BS1, d, 0, 0, 0);
    const float4 bo = *(const float4*)(b_out + 16 * mp + 4 * g);
    *(float4*)(&trans[c][16 * mp + 4 * g]) =
        make_float4((d[0] + bo.x) * ch, (d[1] + bo.y) * ch,
                    (d[2] + bo.z) * ch, (d[3] + bo.w) * ch);
  }
  __syncthreads();
#pragma unroll
  for (int i = 0; i < 4; ++i) {
    const int t = tid + 256 * i;
    const int row = t >> 6, c4i = t & 63;
    const float4 v = *(const float4*)(&trans[row][4 * c4i]);
    *(float4*)(out + (size_t)(bid * 16 + row) * 256 + 4 * c4i) = v;
  }
}

// ---------------------------------------------------------------------------
// Workspace (float offsets): theta [491520] @0, part [2048] @491520,
// Kb [16384 ushort] @493568, Wob [32768 ushort] @501760. Total ~2.03 MB.
// ---------------------------------------------------------------------------
extern "C" void kernel_launch(void* const* d_in, const int* in_sizes, int n_in,
                              void* d_out, int out_size, void* d_ws, size_t ws_size,
                              hipStream_t stream) {
  const float* x     = (const float*)d_in[0];
  const float* W_enc = (const float*)d_in[1];
  const float* b_enc = (const float*)d_in[2];
  const float* K     = (const float*)d_in[3];
  const float* omega = (const float*)d_in[4];
  const float* Kglob = (const float*)d_in[5];
  const float* aplK  = (const float*)d_in[6];
  const float* aplOm = (const float*)d_in[7];
  const float* W1    = (const float*)d_in[8];
  const float* b1    = (const float*)d_in[9];
  const float* W2    = (const float*)d_in[10];
  const float* b2    = (const float*)d_in[11];
  const float* W3    = (const float*)d_in[12];
  const float* b3    = (const float*)d_in[13];
  const float* prior = (const float*)d_in[14];
  const float* noise = (const float*)d_in[15];
  const float* W_out = (const float*)d_in[16];
  const float* b_out = (const float*)d_in[17];

  float* ws    = (float*)d_ws;
  float* theta = ws;
  float* part  = ws + 491520;
  unsigned short* Kb  = (unsigned short*)(ws + 493568);
  unsigned short* Wob = (unsigned short*)(ws + 501760);

  enc_kernel<<<512, 1024, 0, stream>>>(x, W_enc, b_enc, K, W_out,
                                       theta, part, Kb, Wob);
  for (int l = 0; l < 4; ++l) {
    kura_mfma<<<512, 256, 0, stream>>>(theta, noise + (size_t)l * 491520,
                                       Kb, Wob, omega, Kglob, aplK, aplOm,
                                       W1, b1, W2, b2, W3, b3, prior, b_out,
                                       part, (float*)d_out, l);
  }
}